// Round 17
// baseline (90.528 us; speedup 1.0000x reference)
//
#include <hip/hip_runtime.h>
#include <hip/hip_bf16.h>
#include <math.h>

#define HH 256
#define WW 256
#define CIN 16
#define CHID 32
#define CST 48
#define HWPIX (HH * WW)

#define TSX 32                  // tile width
#define TSY 16                  // tile height
#define HX 36                   // halo width  (TSX + 4)
#define HY 20                   // halo height (TSY + 4)
#define NPX (HX * HY)           // 720 staged pixels
#define SP 56                   // s1 pixel stride (elems): ch 0..47 data, 48 = 1.0, 49..55 = 0
#define NKS 14                  // 56 klins: 54 data + bias(klin18) + zero(klin19)
#define RNX 34                  // R-grid width  (TSX + 2)
#define RNY 18                  // R-grid height (TSY + 2)
#define RPOS (RNX * RNY)        // 612 R positions
#define EPS 524                 // sEp channel stride (words) — champion value

// K permutation (ci-block-major, shared by packb and koff):
//   klin  0..17: cib = klin/9 (0,1 = x channels), tap = klin%9
//   klin 18    : bias row (A reads ones slot)
//   klin 19    : zero pad
//   klin 20..37: j=klin-20, cib = 2+j/9, tap = j%9   (prev ch 0..15)
//   klin 38..55: j=klin-38, cib = 4+j/9, tap = j%9   (prev ch 16..31)
// => U-phase needs: ks 0-4 only chunks 0,1 (+ones); ks 5-8 chunks 2,3;
//    ks 9-13 chunks 3,4,5 — enabling staged-pipelined U.

typedef unsigned short u16;
typedef unsigned int u32;
typedef __attribute__((ext_vector_type(8))) short short8;
typedef __attribute__((ext_vector_type(8))) __bf16 bf16x8;
typedef __attribute__((ext_vector_type(4))) float f32x4;
typedef __attribute__((ext_vector_type(2))) float f32x2;
typedef __attribute__((ext_vector_type(4))) unsigned int u32x4;

__device__ __forceinline__ float b2f(u16 h) {
    union { unsigned u; float f; } v; v.u = ((unsigned)h) << 16; return v.f;
}
__device__ __forceinline__ u16 f2b(float f) {
    union { float f; unsigned u; } v; v.f = f;
    unsigned r = v.u + 0x7fffu + ((v.u >> 16) & 1u);
    return (u16)(r >> 16);
}
__device__ __forceinline__ u32 pk2(float a, float bq) {
    u32 r;
    asm("v_cvt_pk_bf16_f32 %0, %1, %2" : "=v"(r) : "v"(a), "v"(bq));
    return r;
}
__device__ __forceinline__ int imin(int a, int b) { return a < b ? a : b; }

// Pre-gather MFMA B fragments per lane with the ci-block-major K permutation;
// activation scale baked into weights; scale*bias at klin 18 (j=0).
__global__ void packb_kernel(const float* __restrict__ wR, const float* __restrict__ wU,
                             const float* __restrict__ wO,
                             const float* __restrict__ bR, const float* __restrict__ bU,
                             const float* __restrict__ bO, u16* __restrict__ pB) {
    int i = blockIdx.x * 256 + threadIdx.x;
    const int TOT = 3 * NKS * 2 * 64 * 8;
    if (i >= TOT) return;
    int conv = i / (NKS * 2 * 64 * 8);
    int r = i - conv * (NKS * 2 * 64 * 8);
    int ks = r / (2 * 64 * 8); r -= ks * (2 * 64 * 8);
    int nf = r / (64 * 8);     r -= nf * (64 * 8);
    int lane = r >> 3, j8 = r & 7;
    int klin = ks * 4 + (lane >> 4);
    int n = nf * 16 + (lane & 15);
    float scale = (conv == 2) ? 2.885390082f : -1.442695041f;
    float val = 0.f;
    if (klin < 18 || klin >= 20) {
        int cib, tap;
        if (klin >= 38)      { int j = klin - 38; int h = j >= 9; cib = 4 + h; tap = j - h * 9; }
        else if (klin >= 20) { int j = klin - 20; int h = j >= 9; cib = 2 + h; tap = j - h * 9; }
        else                 { int h = klin >= 9; cib = h; tap = klin - h * 9; }
        int ci = cib * 8 + j8;
        const float* w = (conv == 0) ? wR : (conv == 1) ? wU : wO;
        val = w[(n * CST + ci) * 9 + tap] * scale;   // OIHW, tap = ky*3+kx
    } else if (klin == 18 && j8 == 0) {
        const float* bb = (conv == 0) ? bR : (conv == 1) ? bU : bO;
        val = bb[n] * scale;
    }
    pB[i] = f2b(val);
}

// Fused ConvGRU, 32x16 tile, 512 threads (8 waves), 2 blocks/CU.
// Champion (r11) structure; only change: staged-pipelined U phase.
__global__ __launch_bounds__(512, 4) void convgru_mfma(
    const float* __restrict__ x, const float* __restrict__ prev,
    const int* __restrict__ mask, const u16* __restrict__ pB,
    float* __restrict__ out)
{
    __shared__ __align__(16) u16 s1[NPX * SP];        // 80640 B
    __shared__ unsigned char smask8[NPX];             // 720 B
    float* sEp = (float*)s1;        // reused after O-phase: 32*524*4 = 67072 B

    // ---- XCD-bijective swizzle: 1024 blocks, one image per XCD ----
    const int flat = (blockIdx.z * gridDim.y + blockIdx.y) * gridDim.x + blockIdx.x;
    const int wid  = ((flat & 7) << 7) | (flat >> 3);
    const int b    = wid >> 7;
    const int y0   = ((wid >> 3) & 15) * TSY;
    const int x0   = (wid & 7) * TSX;

    const int tid = threadIdx.x;
    const int w    = tid >> 6;       // wave id 0..7
    const int lane = tid & 63;
    const int run  = lane >> 4;      // k-run / D-row group
    const int lo   = lane & 15;      // A-row (position) / D-col (channel)

    // ---- per-thread pixel state (persists through staging phases) ----
    bool act1 = (512 + tid) < NPX;
    float mv_[2];
    const float* pb_[2];

    // ---- staging phase A: mask + x channels (chunks 0,1) + ones slot ----
    #pragma unroll
    for (int rp = 0; rp < 2; rp++) {
        int p = rp * 512 + tid;
        bool act = (rp == 0) | act1;
        int pc = act ? p : (NPX - 1);
        int yy = (pc * 911) >> 15;           // /36 (exact for pc<720)
        int xx = pc - yy * HX;
        int gy = y0 + yy - 2, gx = x0 + xx - 2;
        bool in = (unsigned)gy < HH && (unsigned)gx < WW;
        int gyc = in ? gy : 0, gxc = in ? gx : 0;
        int mi = in ? mask[(b * HH + gyc) * WW + gxc] : 0;
        float mv = (float)mi;
        mv_[rp] = mv;
        const float* xb = x + (size_t)b * CIN * HWPIX + gyc * WW + gxc;
        pb_[rp] = prev + (size_t)b * CHID * HWPIX + gyc * WW + gxc;
        if (act) {
            smask8[pc] = (unsigned char)mi;
            u32* dst = (u32*)&s1[pc * SP];
            #pragma unroll
            for (int g = 0; g < 2; g++) {
                const float* src = xb + g * 8 * HWPIX;
                u32x4 w4;
                #pragma unroll
                for (int h = 0; h < 4; h++) {
                    float v0 = src[(2 * h)     * HWPIX] * mv;
                    float v1 = src[(2 * h + 1) * HWPIX] * mv;
                    w4[h] = pk2(v0, v1);
                }
                *(u32x4*)(dst + g * 4) = w4;
            }
            // slots 48..55: {1.0bf16, 0...} -> bias row + K-pad zeros
            *(u32x4*)(dst + 24) = (u32x4){0x3f80u, 0u, 0u, 0u};
        }
    }
    __syncthreads();

    // ---- K-offset table (bytes), new permutation, same for all convs ----
    int koff[NKS];
    #pragma unroll
    for (int ks = 0; ks < NKS; ks++) {
        int klin = ks * 4 + run;
        int off;
        if (klin >= 18 && klin < 20) {
            off = ((HX + 1) * SP + 48) * 2;              // ones slot
        } else {
            int cib, tap;
            if (klin >= 38)      { int j = klin - 38; int h = j >= 9; cib = 4 + h; tap = j - h * 9; }
            else if (klin >= 20) { int j = klin - 20; int h = j >= 9; cib = 2 + h; tap = j - h * 9; }
            else                 { int h = klin >= 9; cib = h; tap = klin - h * 9; }
            int ky = (tap * 11) >> 5, kx = tap - ky * 3;
            off = (((ky * HX + kx) * SP) + cib * 8) * 2;
        }
        koff[ks] = off;
    }

    const char* s1c = (const char*)s1;
    const short8* pB8 = (const short8*)pB;
    const f32x4 z4 = {0.f, 0.f, 0.f, 0.f};
    const int baseU = (((2 * w) + 1) * HX + 1 + lo) * SP * 2;   // bytes, f=0
    const int fOffB[4] = {0, 16 * SP * 2, HX * SP * 2, (HX + 16) * SP * 2};

    // ========== Phase U (staged-pipelined): ks 0-4 | 5-8 | 9-13 ==========
    f32x4 accU[4][2];
    #pragma unroll
    for (int f = 0; f < 4; f++) { accU[f][0] = z4; accU[f][1] = z4; }
    {
        short8 bp[2][2];
        bp[0][0] = pB8[(1 * NKS + 0) * 128 + lane];
        bp[0][1] = pB8[(1 * NKS + 0) * 128 + 64 + lane];
        bp[1][0] = pB8[(1 * NKS + 1) * 128 + lane];
        bp[1][1] = pB8[(1 * NKS + 1) * 128 + 64 + lane];

        auto U_KS = [&](int ks) {
            short8 b0 = bp[ks & 1][0], b1 = bp[ks & 1][1];
            if (ks + 2 < NKS) {
                bp[ks & 1][0] = pB8[(1 * NKS + ks + 2) * 128 + lane];
                bp[ks & 1][1] = pB8[(1 * NKS + ks + 2) * 128 + 64 + lane];
            }
            const char* ap = s1c + baseU + koff[ks];
            __builtin_amdgcn_s_setprio(1);
            #pragma unroll
            for (int f = 0; f < 4; f++) {
                short8 av = *(const short8*)(ap + fOffB[f]);
                bf16x8 a = __builtin_bit_cast(bf16x8, av);
                accU[f][0] = __builtin_amdgcn_mfma_f32_16x16x32_bf16(a, __builtin_bit_cast(bf16x8, b0), accU[f][0], 0, 0, 0);
                accU[f][1] = __builtin_amdgcn_mfma_f32_16x16x32_bf16(a, __builtin_bit_cast(bf16x8, b1), accU[f][1], 0, 0, 0);
            }
            __builtin_amdgcn_s_setprio(0);
        };

        // --- segment 1: issue prev ch 0..15 loads, compute ks 0-4, write chunks 2,3 ---
        {
            float pv[2][16];
            #pragma unroll
            for (int rp = 0; rp < 2; rp++) {
                const float* pbp = pb_[rp];
                #pragma unroll
                for (int h = 0; h < 16; h++) pv[rp][h] = pbp[h * HWPIX];
            }
            #pragma unroll
            for (int ks = 0; ks < 5; ks++) U_KS(ks);
            #pragma unroll
            for (int rp = 0; rp < 2; rp++) {
                if ((rp == 0) | act1) {
                    u32* dst = (u32*)&s1[(rp * 512 + tid) * SP];
                    float mv = mv_[rp];
                    u32x4 w4a, w4b;
                    #pragma unroll
                    for (int h = 0; h < 4; h++) {
                        w4a[h] = pk2(pv[rp][2 * h] * mv, pv[rp][2 * h + 1] * mv);
                        w4b[h] = pk2(pv[rp][8 + 2 * h] * mv, pv[rp][8 + 2 * h + 1] * mv);
                    }
                    *(u32x4*)(dst + 8)  = w4a;   // chunk 2 (ci 16..23)
                    *(u32x4*)(dst + 12) = w4b;   // chunk 3 (ci 24..31)
                }
            }
            __syncthreads();
        }

        // --- segment 2: issue prev ch 16..31 loads, compute ks 5-8, write chunks 4,5 ---
        {
            float pv[2][16];
            #pragma unroll
            for (int rp = 0; rp < 2; rp++) {
                const float* pbp = pb_[rp] + 16 * HWPIX;
                #pragma unroll
                for (int h = 0; h < 16; h++) pv[rp][h] = pbp[h * HWPIX];
            }
            #pragma unroll
            for (int ks = 5; ks < 9; ks++) U_KS(ks);
            #pragma unroll
            for (int rp = 0; rp < 2; rp++) {
                if ((rp == 0) | act1) {
                    u32* dst = (u32*)&s1[(rp * 512 + tid) * SP];
                    float mv = mv_[rp];
                    u32x4 w4a, w4b;
                    #pragma unroll
                    for (int h = 0; h < 4; h++) {
                        w4a[h] = pk2(pv[rp][2 * h] * mv, pv[rp][2 * h + 1] * mv);
                        w4b[h] = pk2(pv[rp][8 + 2 * h] * mv, pv[rp][8 + 2 * h + 1] * mv);
                    }
                    *(u32x4*)(dst + 16) = w4a;   // chunk 4 (ci 32..39)
                    *(u32x4*)(dst + 20) = w4b;   // chunk 5 (ci 40..47)
                }
            }
            __syncthreads();
        }

        // --- segment 3: ks 9-13 (all data staged) ---
        #pragma unroll
        for (int ks = 9; ks < NKS; ks++) U_KS(ks);
    }

    // ========== Phase R: reset conv on 18x34 halo grid (original prev) ==========
    f32x4 accR[5][2];
    #pragma unroll
    for (int f = 0; f < 5; f++) { accR[f][0] = z4; accR[f][1] = z4; }

    int pbase[5];
    #pragma unroll
    for (int f = 0; f < 5; f++) {
        int frag = w + f * 8;
        int idx = imin(frag * 16 + lo, RPOS - 1);
        int ry = (idx * 241) >> 13;          // /34 (exact for idx<624)
        int rx = idx - ry * RNX;
        pbase[f] = (ry * HX + rx) * SP * 2;  // bytes
    }
    {
        short8 bp[2][2];
        bp[0][0] = pB8[(0 * NKS + 0) * 128 + lane];
        bp[0][1] = pB8[(0 * NKS + 0) * 128 + 64 + lane];
        bp[1][0] = pB8[(0 * NKS + 1) * 128 + lane];
        bp[1][1] = pB8[(0 * NKS + 1) * 128 + 64 + lane];
        #pragma unroll
        for (int ks = 0; ks < NKS; ks++) {
            short8 b0 = bp[ks & 1][0], b1 = bp[ks & 1][1];
            if (ks + 2 < NKS) {
                bp[ks & 1][0] = pB8[(0 * NKS + ks + 2) * 128 + lane];
                bp[ks & 1][1] = pB8[(0 * NKS + ks + 2) * 128 + 64 + lane];
            }
            __builtin_amdgcn_s_setprio(1);
            #pragma unroll
            for (int f = 0; f < 5; f++) {
                if (f == 4 && w == 7) continue;   // frag 39 doesn't exist
                short8 av = *(const short8*)(s1c + pbase[f] + koff[ks]);
                bf16x8 a = __builtin_bit_cast(bf16x8, av);
                accR[f][0] = __builtin_amdgcn_mfma_f32_16x16x32_bf16(a, __builtin_bit_cast(bf16x8, b0), accR[f][0], 0, 0, 0);
                accR[f][1] = __builtin_amdgcn_mfma_f32_16x16x32_bf16(a, __builtin_bit_cast(bf16x8, b1), accR[f][1], 0, 0, 0);
            }
            __builtin_amdgcn_s_setprio(0);
        }
    }

    // ---- pm-save (U/O layout): keep each thread's epilogue prev*m values ----
    unsigned pms[4][4];
    #pragma unroll
    for (int f = 0; f < 4; f++) {
        int row = 2 * w + (f >> 1);
        int xh  = (f & 1) * 16;
        #pragma unroll
        for (int reg = 0; reg < 4; reg++) {
            int px = xh + run * 4 + reg;
            int base = ((row + 2) * HX + px + 2) * SP + CIN + lo;
            unsigned a0 = s1[base];
            unsigned a1 = s1[base + 16];
            pms[f][reg] = a0 | (a1 << 16);
        }
    }
    __syncthreads();   // all original-prev reads complete before overwrite

    // ---- R epilogue (RMW): prev*m -> prev*m*sigmoid in place ----
    {
        #pragma unroll
        for (int f = 0; f < 5; f++) {
            if (f == 4 && w == 7) continue;
            int frag = w + f * 8;
            #pragma unroll
            for (int reg = 0; reg < 4; reg++) {
                int idx = frag * 16 + run * 4 + reg;   // m = run*4+reg
                bool valid = idx < RPOS;
                int idc = imin(idx, RPOS - 1);
                int ry = (idc * 241) >> 13, rx = idc - ry * RNX;
                int base = ((ry + 1) * HX + rx + 1) * SP + CIN + lo;
                float sg0 = __builtin_amdgcn_rcpf(1.f + exp2f(accR[f][0][reg]));
                float sg1 = __builtin_amdgcn_rcpf(1.f + exp2f(accR[f][1][reg]));
                float pm0 = b2f(s1[base]);
                float pm1 = b2f(s1[base + 16]);
                u32 pkres = pk2(pm0 * sg0, pm1 * sg1);
                if (valid) {
                    s1[base]      = (u16)pkres;
                    s1[base + 16] = (u16)(pkres >> 16);
                }
            }
        }
    }
    __syncthreads();   // overwrite visible before O-phase

    // ========== Phase O: out conv over [x, prev*reset] — same addressing as U ==========
    f32x4 accO[4][2];
    #pragma unroll
    for (int f = 0; f < 4; f++) { accO[f][0] = z4; accO[f][1] = z4; }
    {
        short8 bp[2][2];
        bp[0][0] = pB8[(2 * NKS + 0) * 128 + lane];
        bp[0][1] = pB8[(2 * NKS + 0) * 128 + 64 + lane];
        bp[1][0] = pB8[(2 * NKS + 1) * 128 + lane];
        bp[1][1] = pB8[(2 * NKS + 1) * 128 + 64 + lane];
        #pragma unroll
        for (int ks = 0; ks < NKS; ks++) {
            short8 b0 = bp[ks & 1][0], b1 = bp[ks & 1][1];
            if (ks + 2 < NKS) {
                bp[ks & 1][0] = pB8[(2 * NKS + ks + 2) * 128 + lane];
                bp[ks & 1][1] = pB8[(2 * NKS + ks + 2) * 128 + 64 + lane];
            }
            const char* ap = s1c + baseU + koff[ks];
            __builtin_amdgcn_s_setprio(1);
            #pragma unroll
            for (int f = 0; f < 4; f++) {
                short8 av = *(const short8*)(ap + fOffB[f]);
                bf16x8 a = __builtin_bit_cast(bf16x8, av);
                accO[f][0] = __builtin_amdgcn_mfma_f32_16x16x32_bf16(a, __builtin_bit_cast(bf16x8, b0), accO[f][0], 0, 0, 0);
                accO[f][1] = __builtin_amdgcn_mfma_f32_16x16x32_bf16(a, __builtin_bit_cast(bf16x8, b1), accO[f][1], 0, 0, 0);
            }
            __builtin_amdgcn_s_setprio(0);
        }
    }
    __syncthreads();   // O-phase LDS reads done; s1 now reusable as sEp

    // ========== Final epilogue: GRU combine -> sEp, b64 stores ==========
    {
        #pragma unroll
        for (int f = 0; f < 4; f++) {
            int row = 2 * w + (f >> 1);
            int xh  = (f & 1) * 16;
            #pragma unroll
            for (int rp2 = 0; rp2 < 2; rp2++) {        // reg pairs (0,1),(2,3)
                int px0 = xh + run * 4 + rp2 * 2;
                #pragma unroll
                for (int nf = 0; nf < 2; nf++) {
                    int c = nf * 16 + lo;
                    f32x2 ov;
                    #pragma unroll
                    for (int q = 0; q < 2; q++) {
                        int reg = rp2 * 2 + q;
                        float mq = (float)smask8[(row + 2) * HX + (xh + run * 4 + reg) + 2];
                        float su = __builtin_amdgcn_rcpf(1.f + exp2f(accU[f][nf][reg]));
                        float th = fmaf(-2.f, __builtin_amdgcn_rcpf(1.f + exp2f(accO[f][nf][reg])), 1.f);
                        float pm = b2f((u16)((pms[f][reg] >> (nf * 16)) & 0xffffu));
                        ov[q] = fmaf(su, fmaf(mq, th, -pm), pm);   // pm + s*(m*th - pm)
                    }
                    *(f32x2*)&sEp[c * EPS + row * TSX + px0] = ov;
                }
            }
        }
    }
    __syncthreads();

    // ---- coalesced stores: 32 floats per row = full 128B lines ----
    #pragma unroll
    for (int r = 0; r < 8; r++) {
        int i = r * 512 + tid;          // 4096 float4 items
        int c = i >> 7;
        int q = (i & 127) * 4;          // row = q>>5, col = q&31
        f32x4 v = *(const f32x4*)&sEp[c * EPS + q];
        int row = q >> 5, col = q & 31;
        *(f32x4*)&out[((size_t)(b * CHID + c) * HH + y0 + row) * WW + x0 + col] = v;
    }
}

extern "C" void kernel_launch(void* const* d_in, const int* in_sizes, int n_in,
                              void* d_out, int out_size, void* d_ws, size_t ws_size,
                              hipStream_t stream) {
    const float* x       = (const float*)d_in[0];
    const float* prev    = (const float*)d_in[1];
    const int*   mask    = (const int*)d_in[2];
    const float* w_reset = (const float*)d_in[3];
    const float* b_reset = (const float*)d_in[4];
    const float* w_upd   = (const float*)d_in[5];
    const float* b_upd   = (const float*)d_in[6];
    const float* w_out   = (const float*)d_in[7];
    const float* b_out   = (const float*)d_in[8];
    float* out = (float*)d_out;

    u16* pB = (u16*)d_ws;                        // 3*14*2*64*8 = 43008 bf16 = 86 KB
    const int TOT = 3 * NKS * 2 * 64 * 8;
    packb_kernel<<<(TOT + 255) / 256, 256, 0, stream>>>(w_reset, w_upd, w_out,
                                                        b_reset, b_upd, b_out, pB);

    dim3 grid(WW / TSX, HH / TSY, 8);            // 8 x 16 x 8 = 1024 blocks
    convgru_mfma<<<grid, 512, 0, stream>>>(x, prev, mask, pB, out);
}

// Round 18
// 78.110 us; speedup vs baseline: 1.1590x; 1.1590x over previous
//
#include <hip/hip_runtime.h>
#include <hip/hip_bf16.h>
#include <math.h>

#define HH 256
#define WW 256
#define CIN 16
#define CHID 32
#define CST 48
#define HWPIX (HH * WW)

#define TSX 32                  // tile width
#define TSY 16                  // tile height
#define HX 36                   // halo width  (TSX + 4)
#define HY 20                   // halo height (TSY + 4)
#define NPX (HX * HY)           // 720 staged pixels
#define SP 56                   // s1 pixel stride (elems): ch 0..47 data, 48 = 1.0, 49..55 = 0
#define NKS 14                  // ceil(432/32) K-steps (pad to 448; k=432 carries bias)
#define RNX 34                  // R-grid width  (TSX + 2)
#define RNY 18                  // R-grid height (TSY + 2)
#define RPOS (RNX * RNY)        // 612 R positions
#define EPS 524                 // sEp channel stride (words)

typedef unsigned short u16;
typedef unsigned int u32;
typedef __attribute__((ext_vector_type(8))) short short8;
typedef __attribute__((ext_vector_type(8))) __bf16 bf16x8;
typedef __attribute__((ext_vector_type(4))) float f32x4;
typedef __attribute__((ext_vector_type(2))) float f32x2;
typedef __attribute__((ext_vector_type(4))) unsigned int u32x4;

__device__ __forceinline__ float b2f(u16 h) {
    union { unsigned u; float f; } v; v.u = ((unsigned)h) << 16; return v.f;
}
__device__ __forceinline__ u16 f2b(float f) {
    union { float f; unsigned u; } v; v.f = f;
    unsigned r = v.u + 0x7fffu + ((v.u >> 16) & 1u);
    return (u16)(r >> 16);
}
// packed RNE f32x2 -> bf16x2 (lo = a, hi = b), single HW instruction
__device__ __forceinline__ u32 pk2(float a, float bq) {
    u32 r;
    asm("v_cvt_pk_bf16_f32 %0, %1, %2" : "=v"(r) : "v"(a), "v"(bq));
    return r;
}
__device__ __forceinline__ int imin(int a, int b) { return a < b ? a : b; }

// Pre-gather MFMA B fragments per lane, with activation scale baked into the
// weights and scale*bias planted at k=432 (A reads constant-1.0 slot there).
// pB[conv][ks][nf][lane][j], 3*14*2*64*8 bf16.
__global__ void packb_kernel(const float* __restrict__ wR, const float* __restrict__ wU,
                             const float* __restrict__ wO,
                             const float* __restrict__ bR, const float* __restrict__ bU,
                             const float* __restrict__ bO, u16* __restrict__ pB) {
    int i = blockIdx.x * 256 + threadIdx.x;
    const int TOT = 3 * NKS * 2 * 64 * 8;
    if (i >= TOT) return;
    int conv = i / (NKS * 2 * 64 * 8);
    int r = i - conv * (NKS * 2 * 64 * 8);
    int ks = r / (2 * 64 * 8); r -= ks * (2 * 64 * 8);
    int nf = r / (64 * 8);     r -= nf * (64 * 8);
    int lane = r >> 3, j = r & 7;
    int k = ks * 32 + (lane >> 4) * 8 + j;
    int n = nf * 16 + (lane & 15);
    // R/U: acc = -log2(e)*(conv+bias) -> sigmoid = rcp(1+exp2(acc))
    // O:   acc = 2*log2(e)*(conv+bias) -> tanh = 1-2*rcp(1+exp2(acc))
    float scale = (conv == 2) ? 2.885390082f : -1.442695041f;
    float val = 0.f;
    if (k < 432) {
        int tap = k / 48, ci = k - tap * 48;
        const float* w = (conv == 0) ? wR : (conv == 1) ? wU : wO;
        val = w[(n * CST + ci) * 9 + tap] * scale;   // OIHW, tap = ky*3+kx
    } else if (k == 432) {
        const float* bb = (conv == 0) ? bR : (conv == 1) ? bU : bO;
        val = bb[n] * scale;
    }
    pB[i] = f2b(val);
}

// Fused ConvGRU, 32x16 tile, 512 threads (8 waves), 2 blocks/CU.
// Champion structure (round-11): stage -> U conv -> R conv (18x34 grid) ->
// pm-save -> R-epilogue in place -> O conv -> GRU combine -> LDS transpose
// -> full-128B-line stores. Bias+activation scale baked into packed B.
__global__ __launch_bounds__(512, 4) void convgru_mfma(
    const float* __restrict__ x, const float* __restrict__ prev,
    const int* __restrict__ mask, const u16* __restrict__ pB,
    float* __restrict__ out)
{
    __shared__ __align__(16) u16 s1[NPX * SP];        // 80640 B
    __shared__ unsigned char smask8[NPX];             // 720 B
    float* sEp = (float*)s1;        // reused after O-phase: 32*524*4 = 67072 B

    // ---- XCD-bijective swizzle: 1024 blocks, one image per XCD ----
    const int flat = (blockIdx.z * gridDim.y + blockIdx.y) * gridDim.x + blockIdx.x;
    const int wid  = ((flat & 7) << 7) | (flat >> 3);
    const int b    = wid >> 7;
    const int y0   = ((wid >> 3) & 15) * TSY;
    const int x0   = (wid & 7) * TSX;

    const int tid = threadIdx.x;
    const int w    = tid >> 6;       // wave id 0..7
    const int lane = tid & 63;
    const int run  = lane >> 4;      // k-run / D-row group
    const int lo   = lane & 15;      // A-row (position) / D-col (channel)

    // ---- staging: pixel-per-thread, channel-inner, packed b128 LDS writes ----
    #pragma unroll
    for (int rp = 0; rp < 2; rp++) {
        int p = rp * 512 + tid;
        bool act = p < NPX;
        int pc = act ? p : (NPX - 1);
        int yy = (pc * 911) >> 15;           // /36 (exact for pc<720)
        int xx = pc - yy * HX;
        int gy = y0 + yy - 2, gx = x0 + xx - 2;
        bool in = (unsigned)gy < HH && (unsigned)gx < WW;
        int gyc = in ? gy : 0, gxc = in ? gx : 0;
        int mi = in ? mask[(b * HH + gyc) * WW + gxc] : 0;
        float mv = (float)mi;
        if (act) {
            smask8[pc] = (unsigned char)mi;
            const float* xb = x    + (size_t)b * CIN  * HWPIX + gyc * WW + gxc;
            const float* pb = prev + (size_t)b * CHID * HWPIX + gyc * WW + gxc;
            u32* dst = (u32*)&s1[pc * SP];
            #pragma unroll
            for (int g = 0; g < 6; g++) {
                const float* src = (g < 2) ? (xb + g * 8 * HWPIX)
                                           : (pb + (g * 8 - 16) * HWPIX);
                u32x4 w4;
                #pragma unroll
                for (int h = 0; h < 4; h++) {
                    float v0 = src[(2 * h)     * HWPIX] * mv;
                    float v1 = src[(2 * h + 1) * HWPIX] * mv;
                    w4[h] = pk2(v0, v1);
                }
                *(u32x4*)(dst + g * 4) = w4;
            }
            // slots 48..55: {1.0bf16, 0...} -> A reads slot48 for the bias row
            *(u32x4*)(dst + 24) = (u32x4){0x3f80u, 0u, 0u, 0u};
        }
    }
    __syncthreads();

    // ---- shared K-offset table (bytes), same for all three convs ----
    int koff[NKS];
    #pragma unroll
    for (int ks = 0; ks < NKS; ks++) {
        int klin = ks * 4 + run;                 // k = 8*klin
        int tap = imin((klin * 43) >> 8, 8);     // klin/6, clamped in pad region
        int ci  = imin((klin - tap * 6) * 8, 40);
        int ky = (tap * 11) >> 5, kx = tap - ky * 3;
        int off = (((ky * HX + kx) * SP) + ci) * 2;
        if (klin == 54) off = ((HX + 1) * SP + 48) * 2;   // bias row -> ones slot
        koff[ks] = off;
    }

    const char* s1c = (const char*)s1;
    const short8* pB8 = (const short8*)pB;
    const f32x4 z4 = {0.f, 0.f, 0.f, 0.f};
    // U/O frag (w,f): out row = 2w + (f>>1), x half = f&1; A col m = lo
    const int baseU = (((2 * w) + 1) * HX + 1 + lo) * SP * 2;   // bytes, f=0
    const int fOffB[4] = {0, 16 * SP * 2, HX * SP * 2, (HX + 16) * SP * 2};

    // ========== Phase U: update conv at 16x32 centers (original prev) ==========
    f32x4 accU[4][2];
    #pragma unroll
    for (int f = 0; f < 4; f++) { accU[f][0] = z4; accU[f][1] = z4; }
    {
        short8 bp[2][2];
        bp[0][0] = pB8[(1 * NKS + 0) * 128 + lane];
        bp[0][1] = pB8[(1 * NKS + 0) * 128 + 64 + lane];
        bp[1][0] = pB8[(1 * NKS + 1) * 128 + lane];
        bp[1][1] = pB8[(1 * NKS + 1) * 128 + 64 + lane];
        #pragma unroll
        for (int ks = 0; ks < NKS; ks++) {
            short8 b0 = bp[ks & 1][0], b1 = bp[ks & 1][1];
            if (ks + 2 < NKS) {
                bp[ks & 1][0] = pB8[(1 * NKS + ks + 2) * 128 + lane];
                bp[ks & 1][1] = pB8[(1 * NKS + ks + 2) * 128 + 64 + lane];
            }
            const char* ap = s1c + baseU + koff[ks];
            __builtin_amdgcn_s_setprio(1);
            #pragma unroll
            for (int f = 0; f < 4; f++) {
                short8 av = *(const short8*)(ap + fOffB[f]);
                bf16x8 a = __builtin_bit_cast(bf16x8, av);
                accU[f][0] = __builtin_amdgcn_mfma_f32_16x16x32_bf16(a, __builtin_bit_cast(bf16x8, b0), accU[f][0], 0, 0, 0);
                accU[f][1] = __builtin_amdgcn_mfma_f32_16x16x32_bf16(a, __builtin_bit_cast(bf16x8, b1), accU[f][1], 0, 0, 0);
            }
            __builtin_amdgcn_s_setprio(0);
        }
    }

    // ========== Phase R: reset conv on 18x34 halo grid (original prev) ==========
    // 612 positions -> 39 frags of 16; wave w owns frags {w + 8f}, f=0..4
    f32x4 accR[5][2];
    #pragma unroll
    for (int f = 0; f < 5; f++) { accR[f][0] = z4; accR[f][1] = z4; }

    int pbase[5];
    #pragma unroll
    for (int f = 0; f < 5; f++) {
        int frag = w + f * 8;
        int idx = imin(frag * 16 + lo, RPOS - 1);
        int ry = (idx * 241) >> 13;          // /34 (exact for idx<624)
        int rx = idx - ry * RNX;
        pbase[f] = (ry * HX + rx) * SP * 2;  // bytes
    }
    {
        short8 bp[2][2];
        bp[0][0] = pB8[(0 * NKS + 0) * 128 + lane];
        bp[0][1] = pB8[(0 * NKS + 0) * 128 + 64 + lane];
        bp[1][0] = pB8[(0 * NKS + 1) * 128 + lane];
        bp[1][1] = pB8[(0 * NKS + 1) * 128 + 64 + lane];
        #pragma unroll
        for (int ks = 0; ks < NKS; ks++) {
            short8 b0 = bp[ks & 1][0], b1 = bp[ks & 1][1];
            if (ks + 2 < NKS) {
                bp[ks & 1][0] = pB8[(0 * NKS + ks + 2) * 128 + lane];
                bp[ks & 1][1] = pB8[(0 * NKS + ks + 2) * 128 + 64 + lane];
            }
            __builtin_amdgcn_s_setprio(1);
            #pragma unroll
            for (int f = 0; f < 5; f++) {
                if (f == 4 && w == 7) continue;   // frag 39 doesn't exist
                short8 av = *(const short8*)(s1c + pbase[f] + koff[ks]);
                bf16x8 a = __builtin_bit_cast(bf16x8, av);
                accR[f][0] = __builtin_amdgcn_mfma_f32_16x16x32_bf16(a, __builtin_bit_cast(bf16x8, b0), accR[f][0], 0, 0, 0);
                accR[f][1] = __builtin_amdgcn_mfma_f32_16x16x32_bf16(a, __builtin_bit_cast(bf16x8, b1), accR[f][1], 0, 0, 0);
            }
            __builtin_amdgcn_s_setprio(0);
        }
    }

    // ---- pm-save (U/O layout): keep each thread's epilogue prev*m values ----
    unsigned pms[4][4];
    #pragma unroll
    for (int f = 0; f < 4; f++) {
        int row = 2 * w + (f >> 1);
        int xh  = (f & 1) * 16;
        #pragma unroll
        for (int reg = 0; reg < 4; reg++) {
            int px = xh + run * 4 + reg;
            int base = ((row + 2) * HX + px + 2) * SP + CIN + lo;
            unsigned a0 = s1[base];
            unsigned a1 = s1[base + 16];
            pms[f][reg] = a0 | (a1 << 16);
        }
    }
    __syncthreads();   // all original-prev reads complete before overwrite

    // ---- R epilogue (RMW): prev*m -> prev*m*sigmoid in place ----
    {
        #pragma unroll
        for (int f = 0; f < 5; f++) {
            if (f == 4 && w == 7) continue;
            int frag = w + f * 8;
            #pragma unroll
            for (int reg = 0; reg < 4; reg++) {
                int idx = frag * 16 + run * 4 + reg;   // m = run*4+reg
                bool valid = idx < RPOS;
                int idc = imin(idx, RPOS - 1);
                int ry = (idc * 241) >> 13, rx = idc - ry * RNX;
                int base = ((ry + 1) * HX + rx + 1) * SP + CIN + lo;
                float sg0 = __builtin_amdgcn_rcpf(1.f + exp2f(accR[f][0][reg]));
                float sg1 = __builtin_amdgcn_rcpf(1.f + exp2f(accR[f][1][reg]));
                float pm0 = b2f(s1[base]);
                float pm1 = b2f(s1[base + 16]);
                u32 pkres = pk2(pm0 * sg0, pm1 * sg1);
                if (valid) {
                    s1[base]      = (u16)pkres;
                    s1[base + 16] = (u16)(pkres >> 16);
                }
            }
        }
    }
    __syncthreads();   // overwrite visible before O-phase

    // ========== Phase O: out conv over [x, prev*reset] — same addressing as U ==========
    f32x4 accO[4][2];
    #pragma unroll
    for (int f = 0; f < 4; f++) { accO[f][0] = z4; accO[f][1] = z4; }
    {
        short8 bp[2][2];
        bp[0][0] = pB8[(2 * NKS + 0) * 128 + lane];
        bp[0][1] = pB8[(2 * NKS + 0) * 128 + 64 + lane];
        bp[1][0] = pB8[(2 * NKS + 1) * 128 + lane];
        bp[1][1] = pB8[(2 * NKS + 1) * 128 + 64 + lane];
        #pragma unroll
        for (int ks = 0; ks < NKS; ks++) {
            short8 b0 = bp[ks & 1][0], b1 = bp[ks & 1][1];
            if (ks + 2 < NKS) {
                bp[ks & 1][0] = pB8[(2 * NKS + ks + 2) * 128 + lane];
                bp[ks & 1][1] = pB8[(2 * NKS + ks + 2) * 128 + 64 + lane];
            }
            const char* ap = s1c + baseU + koff[ks];
            __builtin_amdgcn_s_setprio(1);
            #pragma unroll
            for (int f = 0; f < 4; f++) {
                short8 av = *(const short8*)(ap + fOffB[f]);
                bf16x8 a = __builtin_bit_cast(bf16x8, av);
                accO[f][0] = __builtin_amdgcn_mfma_f32_16x16x32_bf16(a, __builtin_bit_cast(bf16x8, b0), accO[f][0], 0, 0, 0);
                accO[f][1] = __builtin_amdgcn_mfma_f32_16x16x32_bf16(a, __builtin_bit_cast(bf16x8, b1), accO[f][1], 0, 0, 0);
            }
            __builtin_amdgcn_s_setprio(0);
        }
    }
    __syncthreads();   // O-phase LDS reads done; s1 now reusable as sEp

    // ========== Final epilogue: GRU combine -> sEp[c][row][col], b64 stores ==========
    {
        #pragma unroll
        for (int f = 0; f < 4; f++) {
            int row = 2 * w + (f >> 1);
            int xh  = (f & 1) * 16;
            #pragma unroll
            for (int rp = 0; rp < 2; rp++) {           // reg pairs (0,1),(2,3)
                int px0 = xh + run * 4 + rp * 2;
                #pragma unroll
                for (int nf = 0; nf < 2; nf++) {
                    int c = nf * 16 + lo;
                    f32x2 ov;
                    #pragma unroll
                    for (int q = 0; q < 2; q++) {
                        int reg = rp * 2 + q;
                        float mq = (float)smask8[(row + 2) * HX + (xh + run * 4 + reg) + 2];
                        float su = __builtin_amdgcn_rcpf(1.f + exp2f(accU[f][nf][reg]));
                        float th = fmaf(-2.f, __builtin_amdgcn_rcpf(1.f + exp2f(accO[f][nf][reg])), 1.f);
                        float pm = b2f((u16)((pms[f][reg] >> (nf * 16)) & 0xffffu));
                        ov[q] = fmaf(su, fmaf(mq, th, -pm), pm);   // pm + s*(m*th - pm)
                    }
                    *(f32x2*)&sEp[c * EPS + row * TSX + px0] = ov;
                }
            }
        }
    }
    __syncthreads();

    // ---- coalesced stores: 32 floats per row = full 128B lines ----
    #pragma unroll
    for (int r = 0; r < 8; r++) {
        int i = r * 512 + tid;          // 4096 float4 items
        int c = i >> 7;
        int q = (i & 127) * 4;          // row = q>>5, col = q&31
        f32x4 v = *(const f32x4*)&sEp[c * EPS + q];
        int row = q >> 5, col = q & 31;
        *(f32x4*)&out[((size_t)(b * CHID + c) * HH + y0 + row) * WW + x0 + col] = v;
    }
}

extern "C" void kernel_launch(void* const* d_in, const int* in_sizes, int n_in,
                              void* d_out, int out_size, void* d_ws, size_t ws_size,
                              hipStream_t stream) {
    const float* x       = (const float*)d_in[0];
    const float* prev    = (const float*)d_in[1];
    const int*   mask    = (const int*)d_in[2];
    const float* w_reset = (const float*)d_in[3];
    const float* b_reset = (const float*)d_in[4];
    const float* w_upd   = (const float*)d_in[5];
    const float* b_upd   = (const float*)d_in[6];
    const float* w_out   = (const float*)d_in[7];
    const float* b_out   = (const float*)d_in[8];
    float* out = (float*)d_out;

    u16* pB = (u16*)d_ws;                        // 3*14*2*64*8 = 43008 bf16 = 86 KB
    const int TOT = 3 * NKS * 2 * 64 * 8;
    packb_kernel<<<(TOT + 255) / 256, 256, 0, stream>>>(w_reset, w_upd, w_out,
                                                        b_reset, b_upd, b_out, pB);

    dim3 grid(WW / TSX, HH / TSY, 8);            // 8 x 16 x 8 = 1024 blocks
    convgru_mfma<<<grid, 512, 0, stream>>>(x, prev, mask, pB, out);
}